// Round 8
// baseline (325.264 us; speedup 1.0000x reference)
//
#include <hip/hip_runtime.h>
#include <hip/hip_bf16.h>
#include <math.h>

// ---------------------------------------------------------------------------
// GATv2 x2 on MI355X.  N=50000, E=400000, F_in=256, H=4, D=128, F_out=64
// Round 8: GEMM -> transposed-D epilogue (operand-swapped MFMA => 8B vector
// C-stores), barrier moved between ds_read and MFMA (staging overlaps MFMA),
// attn2 -> 4 edges/iter in 16-lane groups. attn1 untouched (balanced pipes).
// ---------------------------------------------------------------------------

#define NEG_SLOPE 0.2f
#define LOG2E 1.4426950408889634f

typedef _Float16 half8 __attribute__((ext_vector_type(8)));
typedef _Float16 h4 __attribute__((ext_vector_type(4)));
typedef _Float16 h2 __attribute__((ext_vector_type(2)));
typedef float f32x4 __attribute__((ext_vector_type(4)));
typedef float f32x2 __attribute__((ext_vector_type(2)));

#if __has_builtin(__builtin_amdgcn_global_load_lds)
#define HAS_GLL 1
__device__ __forceinline__ void gll16(const _Float16* g, _Float16* l) {
    __builtin_amdgcn_global_load_lds(
        (const __attribute__((address_space(1))) unsigned int*)g,
        (__attribute__((address_space(3))) unsigned int*)l, 16, 0, 0);
}
#endif

__device__ __forceinline__ float dot2acc(h2 a, h2 b, float c) {
#if __has_builtin(__builtin_amdgcn_fdot2)
    return __builtin_amdgcn_fdot2(a, b, c, false);
#else
    return fmaf((float)a[1], (float)b[1], fmaf((float)a[0], (float)b[0], c));
#endif
}

__device__ __forceinline__ float fast_exp2(float p) {
#if __has_builtin(__builtin_amdgcn_exp2f)
    return __builtin_amdgcn_exp2f(p);
#else
    return exp2f(p);
#endif
}

__device__ __forceinline__ h2 lrelu2(h2 t, h2 ns2) {
#if __has_builtin(__builtin_elementwise_max)
    return __builtin_elementwise_max(t, t * ns2);
#else
    h2 tn = t * ns2;
    t[0] = (t[0] > tn[0]) ? t[0] : tn[0];
    t[1] = (t[1] > tn[1]) ? t[1] : tn[1];
    return t;
#endif
}

// ---------------- fused cast_x + edge count (independent work) -------------

__global__ __launch_bounds__(256) void k_castx_count(const float* __restrict__ x, _Float16* __restrict__ xh,
                                                     int n8, const int* __restrict__ ei,
                                                     int* __restrict__ counts, int E, int Etot, int gEtot) {
    int b = blockIdx.x;
    if (b < gEtot) {
        int i = b * 256 + threadIdx.x;
        if (i < Etot) {
            int dst = (i < E) ? ei[E + i] : (i - E);
            atomicAdd(&counts[dst], 1);
        }
    } else {
        int i = (b - gEtot) * 256 + threadIdx.x;
        if (i < n8) {
            const float4* p = (const float4*)(x + i * 8);
            float4 a = p[0], c = p[1];
            half8 v;
            v[0] = (_Float16)a.x; v[1] = (_Float16)a.y; v[2] = (_Float16)a.z; v[3] = (_Float16)a.w;
            v[4] = (_Float16)c.x; v[5] = (_Float16)c.y; v[6] = (_Float16)c.z; v[7] = (_Float16)c.w;
            *(half8*)(xh + i * 8) = v;
        }
    }
}

// ---------------- fused cast_w + scan_a (independent work) -----------------

__global__ __launch_bounds__(1024) void k_castw_scana(const int* __restrict__ counts, int* __restrict__ offs,
                                                      int* __restrict__ partial, int n, int nsb,
                                                      const float* __restrict__ Wl1, const float* __restrict__ Wr1,
                                                      const float* __restrict__ Wl2, const float* __restrict__ Wr2,
                                                      _Float16* __restrict__ W1T, _Float16* __restrict__ W2T) {
    __shared__ int buf[1024];
    int b = blockIdx.x, t = threadIdx.x;
    if (b < nsb) {
        int i = b * 1024 + t;
        int v = (i < n) ? counts[i] : 0;
        buf[t] = v;
        __syncthreads();
        #pragma unroll
        for (int off = 1; off < 1024; off <<= 1) {
            int add = (t >= off) ? buf[t - off] : 0;
            __syncthreads();
            buf[t] += add;
            __syncthreads();
        }
        if (i < n) offs[i + 1] = buf[t];
        if (t == 1023) partial[b] = buf[1023];
    } else {
        int i = (b - nsb) * 1024 + t;
        const int T1 = 1024 * 256;
        const int T2 = 128 * 512;
        if (i < T1) {
            int nn = i >> 8, k = i & 255;
            float v = (nn < 512) ? Wl1[k * 512 + nn] : Wr1[k * 512 + (nn - 512)];
            W1T[i] = (_Float16)v;
        } else if (i < T1 + T2) {
            int j = i - T1;
            int nn = j >> 9, k = j & 511;
            float v = (nn < 64) ? Wl2[k * 64 + nn] : Wr2[k * 64 + (nn - 64)];
            W2T[j] = (_Float16)v;
        }
    }
}

// ---------------- merged scan_b + scan_c -----------------------------------

__global__ __launch_bounds__(256) void k_scanbc(int* __restrict__ offs, int* __restrict__ cursor,
                                                const int* __restrict__ partial, int n, int nsb) {
    __shared__ int s[256];
    int t = threadIdx.x;
    int v = (t < nsb) ? partial[t] : 0;
    s[t] = v;
    __syncthreads();
    #pragma unroll
    for (int off = 1; off < 256; off <<= 1) {
        int add = (t >= off) ? s[t - off] : 0;
        __syncthreads();
        s[t] += add;
        __syncthreads();
    }
    int excl = s[t] - v;
    s[t] = excl;
    __syncthreads();
    int i = blockIdx.x * 256 + t;
    if (i == 0) { offs[0] = 0; cursor[0] = 0; }
    if (i < n) {
        int w = offs[i + 1] + s[i >> 10];
        offs[i + 1] = w;
        cursor[i + 1] = w;
    }
}

// ------------------------------- GEMM f16 ----------------------------------
// C[M,N](f16) = A[M,K](f16) @ Bt[N,K](f16)^T. 128x128 tile, BK=32, 512 thr,
// 8 waves in 2(M)x4(N), each 64x32 (4x2 frags, 32 AGPR).
// MFMA operands SWAPPED: D-frag is transposed, so each lane holds 4
// consecutive N-cols of one M-row -> 8B vector C-stores (was 32 scalar).
// 2nd barrier sits between ds_read and MFMA: next iter's global_load_lds is
// issued while this iter's MFMAs run (MFMA touches registers only).

__device__ __forceinline__ void gemm_body(const _Float16* __restrict__ A,
                                          const _Float16* __restrict__ Bt,
                                          _Float16* __restrict__ C,
                                          int M, int N, int K, int ntiles, int blk,
                                          _Float16* As, _Float16* Bs) {
    int tid = threadIdx.x;
    int lane = tid & 63;
    int wave = tid >> 6;                  // 0..7
    int wm = wave >> 2, wn = wave & 3;    // 2 x 4 wave grid
    int l15 = lane & 15, q = lane >> 4;

    int ntile = blk % ntiles;
    int mtile = blk / ntiles;
    int tileM = mtile * 128;
    int tileN = ntile * 128;

    // staging: wave w stages rows [w*16, w*16+16) of A and of B (1 KB each)
    int srow = lane >> 2;                          // 0..15
    int schunk = (lane & 3) ^ ((lane >> 3) & 3);   // swizzled 16B chunk
    const _Float16* gA = A + (long)(tileM + wave * 16 + srow) * K + schunk * 8;
    const _Float16* gB = Bt + (long)(tileN + wave * 16 + srow) * K + schunk * 8;
    _Float16* lA = As + wave * 512;
    _Float16* lB = Bs + wave * 512;

    int aswz = (q ^ ((l15 >> 1) & 3)) * 8;         // reader chunk (halves)

    f32x4 acc[4][2];
    #pragma unroll
    for (int i = 0; i < 4; ++i)
        #pragma unroll
        for (int j = 0; j < 2; ++j)
            acc[i][j] = (f32x4)(0.f);

    for (int k0 = 0; k0 < K; k0 += 32) {
#ifdef HAS_GLL
        gll16(gA + k0, lA);
        gll16(gB + k0, lB);
#else
        half8 va = *(const half8*)(gA + k0);
        half8 vb = *(const half8*)(gB + k0);
        *(half8*)(lA + lane * 8) = va;
        *(half8*)(lB + lane * 8) = vb;
#endif
        __syncthreads();

        half8 af[4], bf[2];
        #pragma unroll
        for (int i = 0; i < 4; ++i)
            af[i] = *(const half8*)(As + (wm * 64 + i * 16 + l15) * 32 + aswz);
        #pragma unroll
        for (int j = 0; j < 2; ++j)
            bf[j] = *(const half8*)(Bs + (wn * 32 + j * 16 + l15) * 32 + aswz);

        __syncthreads();   // reads done -> next iter may restage; MFMAs below
                           // run while next global_load_lds is in flight

        #pragma unroll
        for (int i = 0; i < 4; ++i)
            #pragma unroll
            for (int j = 0; j < 2; ++j)
                acc[i][j] = __builtin_amdgcn_mfma_f32_16x16x32_f16(bf[j], af[i], acc[i][j], 0, 0, 0);
    }

    // transposed-D epilogue: lane holds row (tileM+wm*64+i*16+l15),
    // cols (tileN+wn*32+j*16+q*4 .. +3) -> one 8B store per frag.
    #pragma unroll
    for (int i = 0; i < 4; ++i) {
        int grow = tileM + wm * 64 + i * 16 + l15;
        if (grow < M) {
            #pragma unroll
            for (int j = 0; j < 2; ++j) {
                int gcol = tileN + wn * 32 + j * 16 + q * 4;
                h4 v;
                v[0] = (_Float16)acc[i][j][0];
                v[1] = (_Float16)acc[i][j][1];
                v[2] = (_Float16)acc[i][j][2];
                v[3] = (_Float16)acc[i][j][3];
                *(h4*)(C + (long)grow * N + gcol) = v;
            }
        }
    }
}

// GEMM1 + CSR fill fused: first gb blocks do GEMM, rest do fill.
__global__ __launch_bounds__(512) void k_gemm1_fill(const _Float16* __restrict__ A,
                                                    const _Float16* __restrict__ Bt,
                                                    _Float16* __restrict__ C,
                                                    int M, int N, int K, int ntiles, int gb,
                                                    const int* __restrict__ ei, int* __restrict__ cursor,
                                                    int* __restrict__ csr_src, int E, int Etot) {
    __shared__ _Float16 As[128 * 32];
    __shared__ _Float16 Bs[128 * 32];
    int b = blockIdx.x;
    if (b < gb) {
        gemm_body(A, Bt, C, M, N, K, ntiles, b, As, Bs);
    } else {
        int i = (b - gb) * 512 + threadIdx.x;
        if (i < Etot) {
            int src, dst;
            if (i < E) { src = ei[i]; dst = ei[E + i]; }
            else       { src = i - E; dst = i - E; }
            int pos = atomicAdd(&cursor[dst], 1);
            csr_src[pos] = src;
        }
    }
}

__global__ __launch_bounds__(512) void k_gemm_f16(const _Float16* __restrict__ A,
                                                  const _Float16* __restrict__ Bt,
                                                  _Float16* __restrict__ C,
                                                  int M, int N, int K, int ntiles) {
    __shared__ _Float16 As[128 * 32];
    __shared__ _Float16 Bs[128 * 32];
    gemm_body(A, Bt, C, M, N, K, ntiles, blockIdx.x, As, Bs);
}

// --------------------- fused edge attention, layer 1 -----------------------
// One wave per node, 4 heads (head = lane>>4, 8 ch/lane), 1 edge/iter.
// 32-bit gather offsets, packed f32 acc. (Unchanged — pipes balanced.)

__global__ __launch_bounds__(256) void k_attn1(const _Float16* __restrict__ xlr,
                                               const float* __restrict__ att, const float* __restrict__ b1,
                                               const int* __restrict__ offs, const int* __restrict__ csr_src,
                                               _Float16* __restrict__ hout, int N) {
    int wave = threadIdx.x >> 6;
    int lane = threadIdx.x & 63;
    int node = blockIdx.x * 4 + wave;
    if (node >= N) return;

    int cbase = (lane >> 4) * 128 + (lane & 15) * 8;
    const _Float16* xlr_l = xlr + cbase;           // per-lane base

    half8 xrv8 = *(const half8*)(xlr_l + ((unsigned)node << 10) + 512);
    float4 atv0 = *(const float4*)(att + cbase);
    float4 atv1 = *(const float4*)(att + cbase + 4);
    h2 xr[4], at[4];
    #pragma unroll
    for (int j = 0; j < 4; ++j) {
        xr[j][0] = xrv8[2 * j]; xr[j][1] = xrv8[2 * j + 1];
    }
    at[0][0] = (_Float16)(atv0.x * LOG2E); at[0][1] = (_Float16)(atv0.y * LOG2E);
    at[1][0] = (_Float16)(atv0.z * LOG2E); at[1][1] = (_Float16)(atv0.w * LOG2E);
    at[2][0] = (_Float16)(atv1.x * LOG2E); at[2][1] = (_Float16)(atv1.y * LOG2E);
    at[3][0] = (_Float16)(atv1.z * LOG2E); at[3][1] = (_Float16)(atv1.w * LOG2E);
    const h2 ns2 = {(_Float16)NEG_SLOPE, (_Float16)NEG_SLOPE};

    float l = 0.f;
    f32x2 acc[4];
    #pragma unroll
    for (int j = 0; j < 4; ++j) acc[j] = (f32x2)(0.f);

    int e0 = offs[node], e1 = offs[node + 1];   // e1 > e0 (self-loop)
    int s_next = csr_src[e0];
    int s_next2 = (e0 + 1 < e1) ? csr_src[e0 + 1] : 0;
    half8 xlv = *(const half8*)(xlr_l + ((unsigned)s_next << 10));

    for (int e = e0; e < e1; ++e) {
        half8 cur = xlv;
        int s_pf = s_next2;
        if (e + 2 < e1) s_next2 = csr_src[e + 2];
        if (e + 1 < e1) xlv = *(const half8*)(xlr_l + ((unsigned)s_pf << 10));

        const h2* cp = (const h2*)&cur;
        float p = 0.f;
        #pragma unroll
        for (int j = 0; j < 4; ++j) {
            h2 t = lrelu2(cp[j] + xr[j], ns2);
            p = dot2acc(t, at[j], p);
        }
        #pragma unroll
        for (int off = 1; off <= 8; off <<= 1) p += __shfl_xor(p, off, 64);
        float w = fast_exp2(p);        // == exp(logit): att pre-scaled by log2e
        l += w;
        f32x2 w2 = {w, w};
        #pragma unroll
        for (int j = 0; j < 4; ++j) {
            f32x2 xf = {(float)cur[2 * j], (float)cur[2 * j + 1]};
            acc[j] = w2 * xf + acc[j];
        }
    }

    float inv = 1.f / (l + 1e-16f);
    float4 b1v0 = *(const float4*)(b1 + cbase);
    float4 b1v1 = *(const float4*)(b1 + cbase + 4);
    float bb[8] = {b1v0.x, b1v0.y, b1v0.z, b1v0.w, b1v1.x, b1v1.y, b1v1.z, b1v1.w};
    half8 ov;
    #pragma unroll
    for (int j = 0; j < 8; ++j) {
        float o = fmaf(acc[j >> 1][j & 1], inv, bb[j]);
        o = (o > 0.f) ? o : (__expf(o) - 1.f);
        ov[j] = (_Float16)o;
    }
    *(half8*)(hout + (long)node * 512 + cbase) = ov;
}

// --------------------- fused edge attention, layer 2 -----------------------
// One wave per node, FOUR edges/iter: 16-lane group per edge, 4 ch/lane
// (D=64). Reduce = 4 xor-shuffles within group; cross-group merge once.

__global__ __launch_bounds__(256) void k_attn2(const _Float16* __restrict__ xlr2,
                                               const float* __restrict__ att, const float* __restrict__ b2,
                                               const int* __restrict__ offs, const int* __restrict__ csr_src,
                                               float* __restrict__ out, int N) {
    int wave = threadIdx.x >> 6;
    int lane = threadIdx.x & 63;
    int node = blockIdx.x * 4 + wave;
    if (node >= N) return;

    int g  = lane >> 4;            // edge slot 0..3
    int gl = lane & 15;
    int ch = gl * 4;
    const _Float16* base = xlr2 + ch;

    h4 xr4 = *(const h4*)(base + ((unsigned)node << 7) + 64);
    h2 xr0 = {xr4[0], xr4[1]}, xr1 = {xr4[2], xr4[3]};
    float4 atf = *(const float4*)(att + ch);
    h2 at0; at0[0] = (_Float16)(atf.x * LOG2E); at0[1] = (_Float16)(atf.y * LOG2E);
    h2 at1; at1[0] = (_Float16)(atf.z * LOG2E); at1[1] = (_Float16)(atf.w * LOG2E);
    const h2 ns2 = {(_Float16)NEG_SLOPE, (_Float16)NEG_SLOPE};

    float l = 0.f;
    f32x2 acc0 = (f32x2)(0.f), acc1 = (f32x2)(0.f);
    int e0 = offs[node], e1 = offs[node + 1];
    int e = e0 + g;
    h4 cv;
    if (e < e1) {
        int s = csr_src[e];
        cv = *(const h4*)(base + ((unsigned)s << 7));
    }
    while (e < e1) {
        h4 u = cv;
        int en = e + 4;
        if (en < e1) {
            int s = csr_src[en];
            cv = *(const h4*)(base + ((unsigned)s << 7));
        }
        h2 u0 = {u[0], u[1]}, u1 = {u[2], u[3]};
        h2 t0 = lrelu2(u0 + xr0, ns2);
        h2 t1 = lrelu2(u1 + xr1, ns2);
        float p = dot2acc(t0, at0, 0.f);
        p = dot2acc(t1, at1, p);
        p += __shfl_xor(p, 1, 64);
        p += __shfl_xor(p, 2, 64);
        p += __shfl_xor(p, 4, 64);
        p += __shfl_xor(p, 8, 64);
        float w = fast_exp2(p);
        l += w;
        f32x2 w2 = {w, w};
        f32x2 x0 = {(float)u[0], (float)u[1]};
        f32x2 x1 = {(float)u[2], (float)u[3]};
        acc0 = w2 * x0 + acc0;
        acc1 = w2 * x1 + acc1;
        e = en;
    }
    // merge 4 groups
    float a0 = acc0[0], a1 = acc0[1], a2 = acc1[0], a3 = acc1[1];
    l  += __shfl_xor(l, 16, 64);  l  += __shfl_xor(l, 32, 64);
    a0 += __shfl_xor(a0, 16, 64); a0 += __shfl_xor(a0, 32, 64);
    a1 += __shfl_xor(a1, 16, 64); a1 += __shfl_xor(a1, 32, 64);
    a2 += __shfl_xor(a2, 16, 64); a2 += __shfl_xor(a2, 32, 64);
    a3 += __shfl_xor(a3, 16, 64); a3 += __shfl_xor(a3, 32, 64);
    if (g == 0) {
        float inv = 1.f / (l + 1e-16f);
        float4 bv = *(const float4*)(b2 + ch);
        float4 o;
        o.x = fmaf(a0, inv, bv.x);
        o.y = fmaf(a1, inv, bv.y);
        o.z = fmaf(a2, inv, bv.z);
        o.w = fmaf(a3, inv, bv.w);
        *(float4*)(out + (long)node * 64 + ch) = o;
    }
}

// ---------------------------------------------------------------------------

extern "C" void kernel_launch(void* const* d_in, const int* in_sizes, int n_in,
                              void* d_out, int out_size, void* d_ws, size_t ws_size,
                              hipStream_t stream) {
    const float* x    = (const float*)d_in[0];
    const int*   ei   = (const int*)d_in[1];
    const float* Wl1  = (const float*)d_in[2];
    const float* Wr1  = (const float*)d_in[3];
    const float* att1 = (const float*)d_in[4];
    const float* b1   = (const float*)d_in[5];
    const float* Wl2  = (const float*)d_in[6];
    const float* Wr2  = (const float*)d_in[7];
    const float* att2 = (const float*)d_in[8];
    const float* b2   = (const float*)d_in[9];
    float* out = (float*)d_out;

    const int F_IN = 256;
    int N = in_sizes[0] / F_IN;   // 50000
    int E = in_sizes[1] / 2;      // 400000
    int Etot = E + N;
    int nScanBlocks = (N + 1023) / 1024;
    int mtiles = (N + 127) / 128;
    int Mpad = mtiles * 128;      // A buffers padded so GEMM can load OOB rows

    char* p = (char*)d_ws;
    auto carve = [&](size_t bytes) -> void* {
        void* r = (void*)p;
        p += (bytes + 255) & ~(size_t)255;
        return r;
    };
    _Float16* xh   = (_Float16*)carve((size_t)Mpad * 256 * 2);
    _Float16* W1T  = (_Float16*)carve((size_t)1024 * 256 * 2);
    _Float16* W2T  = (_Float16*)carve((size_t)128 * 512 * 2);
    _Float16* C1   = (_Float16*)carve((size_t)N * 1024 * 2);
    _Float16* h    = (_Float16*)carve((size_t)Mpad * 512 * 2);
    _Float16* C2   = (_Float16*)carve((size_t)N * 128 * 2);
    int* counts  = (int*)carve((size_t)N * 4);
    int* offs    = (int*)carve((size_t)(N + 1) * 4);
    int* cursor  = (int*)carve((size_t)(N + 1) * 4);
    int* partial = (int*)carve((size_t)nScanBlocks * 4);
    int* csr     = (int*)carve((size_t)Etot * 4);

    int gN    = (N + 255) / 256;
    int gEtot = (Etot + 255) / 256;
    int n8    = N * 256 / 8;
    int gCast = (n8 + 255) / 256;

    hipMemsetAsync(counts, 0, (size_t)N * 4, stream);

    // cast_x || count  (independent)
    k_castx_count<<<gEtot + gCast, 256, 0, stream>>>(x, xh, n8, ei, counts, E, Etot, gEtot);

    // cast_w || scan_a  (independent)
    {
        int total = 1024 * 256 + 128 * 512;
        int gW = (total + 1023) / 1024;
        k_castw_scana<<<nScanBlocks + gW, 1024, 0, stream>>>(counts, offs, partial, N, nScanBlocks,
                                                             Wl1, Wr1, Wl2, Wr2, W1T, W2T);
    }
    // merged scan_b + scan_c
    k_scanbc<<<gN, 256, 0, stream>>>(offs, cursor, partial, N, nScanBlocks);

    // layer 1 GEMM (N-tile inner for A reuse) || CSR fill (independent)
    {
        int gb = mtiles * 8;
        int fillBlocks = (Etot + 511) / 512;
        k_gemm1_fill<<<gb + fillBlocks, 512, 0, stream>>>(xh, W1T, C1, N, 1024, 256, 8, gb,
                                                          ei, cursor, csr, E, Etot);
    }
    k_attn1<<<(N + 3) / 4, 256, 0, stream>>>(C1, att1, b1, offs, csr, h, N);

    // layer 2
    k_gemm_f16<<<mtiles, 512, 0, stream>>>(h, W2T, C2, N, 128, 512, 1);
    k_attn2<<<(N + 3) / 4, 256, 0, stream>>>(C2, att2, b2, offs, csr, out, N);
}